// Round 13
// baseline (210.297 us; speedup 1.0000x reference)
//
#include <hip/hip_runtime.h>
#include <hip/hip_bf16.h>
#include <stdint.h>

#define NE    64
#define DIN   512
#define DOUT  512
#define TTOK  131072
#define BM    128
#define BN    256
#define BK    32
#define NK    (DIN / BK)              // 16 K-steps
#define TILES_TOTAL (TTOK / BM + NE)  // 1088
#define NXCD  8
#define TPX   (TILES_TOTAL / NXCD)    // 136

typedef __bf16 bf16x8_t __attribute__((ext_vector_type(8)));
typedef float  f32x4_t  __attribute__((ext_vector_type(4)));

// LDS (64 KB -> 2 blocks/CU = 16 waves):
//   A dbuf: 2 x 8192   (64 LDS rows x 128B bf16; row lr holds A-rows lr & lr+64)
//   B ring: 3 x 16384  (128 LDS rows x 128B bf16; row lr holds dout lr & lr+128)
// Both use the proven (lr&7)<<4 XOR swizzle over 128B rows (R12: conflicts == 0).
#define ABUF(i) ((i) * 8192)
#define BBUF(i) (16384 + (i) * 16384)
#define LDS_BYTES 65536

#define WAITV(n) asm volatile("s_waitcnt vmcnt(" #n ")" ::: "memory")
#define LGKM0()  asm volatile("s_waitcnt lgkmcnt(0)" ::: "memory")
#define SB() __builtin_amdgcn_sched_barrier(0)

// ws layout: ws[0] = ntiles; tile table (int4) at ws+4; bf16 weight at +32KB
#define WBF_OFF 32768

__global__ void setup_tiles(const int* __restrict__ cnt, int* __restrict__ ws) {
    int e = threadIdx.x;
    if (e >= NE) return;
    int off = 0, tbase = 0;
    for (int i = 0; i < e; ++i) {
        int c = cnt[i];
        off += c;
        tbase += (c + (BM - 1)) / BM;
    }
    int c = cnt[e];
    int nt = (c + (BM - 1)) / BM;
    int* tbl = ws + 4;
    for (int t = 0; t < nt; ++t) {
        int idx = tbase + t;
        tbl[4 * idx + 0] = e;
        tbl[4 * idx + 1] = off + t * BM;
        tbl[4 * idx + 2] = off + c;
        tbl[4 * idx + 3] = 0;
    }
    if (e == NE - 1) ws[0] = tbase + nt;
}

// weight fp32 -> bf16, streaming
__global__ __launch_bounds__(256) void wcvt(const float* __restrict__ w,
                                            __bf16* __restrict__ wbf) {
    const size_t stride = (size_t)gridDim.x * 256;
    size_t i = (size_t)blockIdx.x * 256 + threadIdx.x;
    const size_t n8 = (size_t)NE * DOUT * DIN / 8;
    for (; i < n8; i += stride) {
        f32x4_t a = *(const f32x4_t*)(w + i * 8);
        f32x4_t b = *(const f32x4_t*)(w + i * 8 + 4);
        bf16x8_t h;
#pragma unroll
        for (int j = 0; j < 4; ++j) {
            h[j]     = (__bf16)a[j];
            h[4 + j] = (__bf16)b[j];
        }
        *(bf16x8_t*)(wbf + i * 8) = h;
    }
}

__device__ __forceinline__ void gload16(const void* g, uint8_t* l) {
    __builtin_amdgcn_global_load_lds(
        (const __attribute__((address_space(1))) uint32_t*)g,
        (__attribute__((address_space(3))) uint32_t*)l, 16, 0, 0);
}

__global__ __launch_bounds__(512, 4) void moe_gemm(
    const float* __restrict__ inp,
    const __bf16* __restrict__ wbf,
    const float* __restrict__ bias,
    const int* __restrict__ ws,
    float* __restrict__ out)
{
    __shared__ __align__(16) uint8_t smem[LDS_BYTES];

    const int bid  = blockIdx.x;
    const int xcd  = bid & (NXCD - 1);
    const int slot = bid >> 3;                 // 0..271
    const int tile = xcd * TPX + (slot >> 1);
    const int n0   = (slot & 1) * BN;

    const int ntiles = ws[0];
    if (tile >= ntiles) return;
    const int4 ti = ((const int4*)(ws + 4))[tile];
    const int e = ti.x, row0 = ti.y, row_end = ti.z;

    const int tid  = threadIdx.x;
    const int lane = tid & 63;
    const int wave = tid >> 6;         // 0..7
    const int dr = lane >> 3;          // row-in-8-group (DMA dest)
    const int ac = lane & 7;           // dest 16B chunk (linear)
    const int u  = ac ^ dr;            // logical chunk (group base % 8 == 0)

    // ---- B staging (R12-proven): 2 gload16/wave into 128-row paired layout ----
    const __bf16* bsrc[2];
#pragma unroll
    for (int i = 0; i < 2; ++i) {
        int lr = wave * 16 + i * 8 + dr;
        int dout = n0 + lr + ((u >> 2) << 7);
        bsrc[i] = wbf + (size_t)(e * DOUT + dout) * DIN + (u & 3) * 8;
    }
    auto issueB = [&](int t, int slot3) {
        uint8_t* dst = smem + BBUF(slot3) + wave * 2048;
#pragma unroll
        for (int i = 0; i < 2; ++i)
            gload16(bsrc[i] + t * BK, dst + i * 1024);
    };

    // ---- A staging (R12-proven): reg fp32 -> bf16 -> one swizzled ds_write ----
    const int alr = tid >> 3;          // 0..63
    const int acn = tid & 7;           // chunk 0..7
    int agrow = row0 + alr + ((acn >> 2) << 6);
    if (agrow > row_end - 1) agrow = row_end - 1;   // clamp (C-stores guarded)
    const float* asrc = inp + (size_t)agrow * DIN + (acn & 3) * 8;
    const int awoff = alr * 128 + ((acn * 16) ^ ((alr & 7) << 4));

    f32x4_t ra[2][2];                  // [parity][chunk] : 2-step A prefetch
    auto loadA = [&](int t) {
        ra[t & 1][0] = *(const f32x4_t*)(asrc + t * BK);
        ra[t & 1][1] = *(const f32x4_t*)(asrc + t * BK + 4);
    };
    auto writeA = [&](int t) {         // writes abuf (t&1) from ra[t&1]
        bf16x8_t h;
#pragma unroll
        for (int j = 0; j < 4; ++j) {
            h[j]     = (__bf16)ra[t & 1][0][j];
            h[4 + j] = (__bf16)ra[t & 1][1][j];
        }
        *(bf16x8_t*)(smem + ABUF(t & 1) + awoff) = h;
    };

    // ---- compute: wave owns 64 rows x 64 cols (4 x 4 frags), all-bf16 LDS ----
    const int wr = (wave >> 2) * 64;   // 2 M-bands of 64
    const int wc = (wave & 3) * 64;    // 4 N-bands of 64
    const int frow = lane & 15;
    const int kg   = lane >> 4;

    f32x4_t acc[4][4] = {};

    auto compute = [&](int t) {
        const int abuf = t & 1, bs = t % 3;
        bf16x8_t af[4], bg[4];
#pragma unroll
        for (int m = 0; m < 4; ++m) {
            const int row = wr + m * 16 + frow;     // A-row in tile (0..127)
            const int lr  = row & 63;
            const int h   = row >> 6;
            af[m] = *(const bf16x8_t*)(smem + ABUF(abuf) + lr * 128 +
                                       ((h * 64 + kg * 16) ^ ((lr & 7) << 4)));
        }
#pragma unroll
        for (int n = 0; n < 4; ++n) {
            const int row = wc + n * 16 + frow;     // dout-row in tile (0..255)
            const int lr  = row & 127;
            const int h   = row >> 7;
            bg[n] = *(const bf16x8_t*)(smem + BBUF(bs) + lr * 128 +
                                       ((h * 64 + kg * 16) ^ ((lr & 7) << 4)));
        }
        __builtin_amdgcn_s_setprio(1);
#pragma unroll
        for (int m = 0; m < 4; ++m)
#pragma unroll
            for (int n = 0; n < 4; ++n)
                acc[m][n] = __builtin_amdgcn_mfma_f32_16x16x32_bf16(
                    af[m], bg[n], acc[m][n], 0, 0, 0);
        __builtin_amdgcn_s_setprio(0);
    };

    // ---- counted-vmcnt pipeline (T4) on R12's structure.
    // Step t issue order: loadA(t+2) x2, issueB(t+2) x2  (4 newest VMEM).
    // End-of-step WAITV(4) certifies everything through issueB(t+1) --
    // i.e. B(t+1) LDS-resident and ra(t+1) in regs, both issued at t-1
    // (~1.5 steps of flight) -- while t+2's 4 ops stay airborne.
    // LDS-write hazards: every write targets a slot whose readers passed
    // the previous barrier (A dbuf: step t-1; B ring-3: step t-1). ----
    loadA(0); SB();
    issueB(0, 0); SB();
    loadA(1); SB();
    issueB(1, 1); SB();
    writeA(0);                        // auto vmcnt(6): waits ra(0) only
    WAITV(4); LGKM0(); SB();          // B(0) resident; A(1)+B(1) fly
    __builtin_amdgcn_s_barrier();
#pragma unroll
    for (int t = 0; t < NK; ++t) {
        if (t + 2 < NK) {
            loadA(t + 2); SB();
            issueB(t + 2, (t + 2) % 3); SB();
        }
        compute(t);
        if (t + 1 < NK) {
            writeA(t + 1);            // auto vmcnt: ra(t+1) certified
            if (t + 2 < NK) { WAITV(4); } else { WAITV(0); }
            LGKM0(); SB();
            __builtin_amdgcn_s_barrier();
        }
    }

    // ---- epilogue: C/D layout col = lane&15, row = (lane>>4)*4 + j [m89] ----
    const int crow = kg * 4;
    const int ccol = frow;
    float bv[4];
#pragma unroll
    for (int n = 0; n < 4; ++n)
        bv[n] = bias[e * DOUT + n0 + wc + n * 16 + ccol];
#pragma unroll
    for (int m = 0; m < 4; ++m) {
#pragma unroll
        for (int j = 0; j < 4; ++j) {
            const int grow = row0 + wr + m * 16 + crow + j;
            if (grow < row_end) {
                float* orow = out + (size_t)grow * DOUT + n0 + wc + ccol;
#pragma unroll
                for (int n = 0; n < 4; ++n)
                    orow[n * 16] = acc[m][n][j] + bv[n];
            }
        }
    }
}

extern "C" void kernel_launch(void* const* d_in, const int* in_sizes, int n_in,
                              void* d_out, int out_size, void* d_ws, size_t ws_size,
                              hipStream_t stream) {
    const float* inp    = (const float*)d_in[0];
    const float* weight = (const float*)d_in[1];
    const float* bias   = (const float*)d_in[2];
    const int* cnt      = (const int*)d_in[3];   // int64 in reference, delivered as int32
    float* out = (float*)d_out;
    int* ws = (int*)d_ws;
    __bf16* wbf = (__bf16*)((char*)d_ws + WBF_OFF);

    hipLaunchKernelGGL(setup_tiles, dim3(1), dim3(64), 0, stream, cnt, ws);
    hipLaunchKernelGGL(wcvt, dim3(2048), dim3(256), 0, stream, weight, wbf);
    hipLaunchKernelGGL(moe_gemm, dim3(TILES_TOTAL * 2), dim3(512), 0, stream,
                       inp, wbf, bias, ws, out);
}

// Round 14
// 192.809 us; speedup vs baseline: 1.0907x; 1.0907x over previous
//
#include <hip/hip_runtime.h>
#include <hip/hip_bf16.h>
#include <stdint.h>

#define NE    64
#define DIN   512
#define DOUT  512
#define TTOK  131072
#define BM    256
#define BN    256
#define BK    64
#define NKT   (DIN / BK)              // 8 K-tiles
#define TILES_TOTAL (TTOK / BM + NE)  // 576
#define NXCD  8
#define TPX   (TILES_TOTAL / NXCD)    // 72

typedef __bf16 bf16x8_t __attribute__((ext_vector_type(8)));
typedef float  f32x4_t  __attribute__((ext_vector_type(4)));

// LDS 128 KB: A dbuf 2 x 32 KB (256 rows x 128B bf16), B dbuf 2 x 32 KB
// (256 rows x 128B bf16). Proven (row&7)<<4 XOR swizzle on 128B rows.
#define ABUF(i) ((i) * 32768)
#define BBUF(i) (65536 + (i) * 32768)
#define LDS_BYTES 131072

#define WAITV(n) asm volatile("s_waitcnt vmcnt(" #n ")" ::: "memory")
#define LGKM0()  asm volatile("s_waitcnt lgkmcnt(0)" ::: "memory")
#define SB() __builtin_amdgcn_sched_barrier(0)
#define BAR() __builtin_amdgcn_s_barrier()

// ws layout: ws[0] = ntiles; tile table (int4) at ws+4; bf16 weight at +32KB
#define WBF_OFF 32768

__global__ void setup_tiles(const int* __restrict__ cnt, int* __restrict__ ws) {
    int e = threadIdx.x;
    if (e >= NE) return;
    int off = 0, tbase = 0;
    for (int i = 0; i < e; ++i) {
        int c = cnt[i];
        off += c;
        tbase += (c + (BM - 1)) / BM;
    }
    int c = cnt[e];
    int nt = (c + (BM - 1)) / BM;
    int* tbl = ws + 4;
    for (int t = 0; t < nt; ++t) {
        int idx = tbase + t;
        tbl[4 * idx + 0] = e;
        tbl[4 * idx + 1] = off + t * BM;
        tbl[4 * idx + 2] = off + c;
        tbl[4 * idx + 3] = 0;
    }
    if (e == NE - 1) ws[0] = tbase + nt;
}

// weight fp32 -> bf16, streaming
__global__ __launch_bounds__(256) void wcvt(const float* __restrict__ w,
                                            __bf16* __restrict__ wbf) {
    const size_t stride = (size_t)gridDim.x * 256;
    size_t i = (size_t)blockIdx.x * 256 + threadIdx.x;
    const size_t n8 = (size_t)NE * DOUT * DIN / 8;
    for (; i < n8; i += stride) {
        f32x4_t a = *(const f32x4_t*)(w + i * 8);
        f32x4_t b = *(const f32x4_t*)(w + i * 8 + 4);
        bf16x8_t h;
#pragma unroll
        for (int j = 0; j < 4; ++j) {
            h[j]     = (__bf16)a[j];
            h[4 + j] = (__bf16)b[j];
        }
        *(bf16x8_t*)(wbf + i * 8) = h;
    }
}

__device__ __forceinline__ void gload16(const void* g, uint8_t* l) {
    __builtin_amdgcn_global_load_lds(
        (const __attribute__((address_space(1))) uint32_t*)g,
        (__attribute__((address_space(3))) uint32_t*)l, 16, 0, 0);
}

__global__ __launch_bounds__(512, 2) void moe_gemm(
    const float* __restrict__ inp,
    const __bf16* __restrict__ wbf,
    const float* __restrict__ bias,
    const int* __restrict__ ws,
    float* __restrict__ out)
{
    __shared__ __align__(16) uint8_t smem[LDS_BYTES];

    const int bid  = blockIdx.x;
    const int xcd  = bid & (NXCD - 1);
    const int slot = bid >> 3;                 // 0..143
    const int tile = xcd * TPX + (slot >> 1);
    const int n0   = (slot & 1) * BN;

    const int ntiles = ws[0];
    if (tile >= ntiles) return;
    const int4 ti = ((const int4*)(ws + 4))[tile];
    const int e = ti.x, row0 = ti.y, row_end = ti.z;

    const int tid  = threadIdx.x;
    const int lane = tid & 63;
    const int wave = tid >> 6;         // 0..7

    // ---- A staging: thread -> (arow = tid>>3 (+64i), acn = tid&7).
    // Per K-tile: 8 f32x4 global loads -> cvt -> 4 swizzled ds_write_b128
    // (per-wave write pattern identical to R12's measured-conflict-free). ----
    const int arow = tid >> 3;         // 0..63
    const int acn  = tid & 7;
    const int aswz = (arow & 7) << 4;  // (row&7) invariant under +64i
    const float* asrc[4];
    int awoff[4];
#pragma unroll
    for (int i = 0; i < 4; ++i) {
        int r = arow + 64 * i;
        int grow = row0 + r;
        if (grow > row_end - 1) grow = row_end - 1;   // clamp (C-stores guarded)
        asrc[i]  = inp + (size_t)grow * DIN + acn * 8;
        awoff[i] = r * 128 + ((acn * 16) ^ aswz);
    }
    f32x4_t ra[8];
    auto issueAglb = [&](int tk) {
#pragma unroll
        for (int i = 0; i < 4; ++i) {
            ra[2 * i]     = *(const f32x4_t*)(asrc[i] + tk * BK);
            ra[2 * i + 1] = *(const f32x4_t*)(asrc[i] + tk * BK + 4);
        }
    };
    auto cvtWriteA = [&](int buf) {
#pragma unroll
        for (int i = 0; i < 4; ++i) {
            bf16x8_t h;
#pragma unroll
            for (int j = 0; j < 4; ++j) {
                h[j]     = (__bf16)ra[2 * i][j];
                h[4 + j] = (__bf16)ra[2 * i + 1][j];
            }
            *(bf16x8_t*)(smem + ABUF(buf) + awoff[i]) = h;
        }
    };

    // ---- B staging: 4 gload16/wave per K-tile; linear dest, preswizzled src.
    // gload16 i covers LDS rows wave*32 + i*8 + dr; row holds wbf col n0+row. ----
    const int dr = lane >> 3;
    const int ac = lane & 7;
    const int u  = ac ^ dr;            // logical k-chunk (group base % 8 == 0)
    const __bf16* bsrc[4];
#pragma unroll
    for (int i = 0; i < 4; ++i) {
        int row = wave * 32 + i * 8 + dr;
        bsrc[i] = wbf + (size_t)(e * DOUT + n0 + row) * DIN + u * 8;
    }
    auto issueB = [&](int tk, int buf) {
        uint8_t* dst = smem + BBUF(buf) + wave * 4096;
#pragma unroll
        for (int i = 0; i < 4; ++i)
            gload16(bsrc[i] + tk * BK, dst + i * 1024);
    };

    // ---- compute: wave owns 128 rows x 64 cols; quadrant q = m {2q,2q+1} ----
    const int wr = (wave >> 2) * 128;  // 2 M-groups
    const int wc = (wave & 3) * 64;    // 4 N-groups
    const int frow = lane & 15;
    const int kg   = lane >> 4;

    f32x4_t acc[8][4] = {};
    bf16x8_t bg[4][2], af[2][2];

    auto dsrB = [&](int buf) {
#pragma unroll
        for (int n = 0; n < 4; ++n) {
            const int row = wc + n * 16 + frow;
            const uint8_t* p = smem + BBUF(buf) + row * 128;
            const int sw = (row & 7) << 4;
#pragma unroll
            for (int ks = 0; ks < 2; ++ks)
                bg[n][ks] = *(const bf16x8_t*)(p + ((ks * 64 + kg * 16) ^ sw));
        }
    };
    auto dsrA = [&](int buf, int q) {
#pragma unroll
        for (int j = 0; j < 2; ++j) {
            const int row = wr + (2 * q + j) * 16 + frow;
            const uint8_t* p = smem + ABUF(buf) + row * 128;
            const int sw = (row & 7) << 4;
#pragma unroll
            for (int ks = 0; ks < 2; ++ks)
                af[j][ks] = *(const bf16x8_t*)(p + ((ks * 64 + kg * 16) ^ sw));
        }
    };
    auto mfmaQ = [&](int q) {
        __builtin_amdgcn_s_setprio(1);
#pragma unroll
        for (int ks = 0; ks < 2; ++ks)
#pragma unroll
            for (int j = 0; j < 2; ++j)
#pragma unroll
                for (int n = 0; n < 4; ++n)
                    acc[2 * q + j][n] = __builtin_amdgcn_mfma_f32_16x16x32_bf16(
                        af[j][ks], bg[n][ks], acc[2 * q + j][n], 0, 0, 0);
        __builtin_amdgcn_s_setprio(0);
    };

    // ---- prologue: buf0 = tile0; A(1) global loads in flight ----
    issueAglb(0);
    issueB(0, 0);
    WAITV(4); SB();                    // certify A(0) regs; B(0) DMA flies
    cvtWriteA(0);
    issueAglb(1);
    WAITV(8); LGKM0(); SB();           // certify B(0); keep A(1) x8 in flight
    BAR();

    // ---- main: 8 K-tiles x 4 phases. Steady-state per-wave vmcnt FIFO:
    // ph0 entry: [A(t+1) x8] -> WAITV0 certifies (issued t-1 ph1, ~7 phases old)
    // ph3 entry: [B(t+1) x4, A(t+2) x8] -> WAITV(8) certifies B(t+1). ----
#pragma unroll
    for (int t = 0; t < NKT; ++t) {
        const int buf = t & 1;
        // phase 0: publish A(t+1), launch B(t+1); read B-frags + A-quad0
        if (t + 1 < NKT) {
            WAITV(0); SB();
            cvtWriteA(buf ^ 1);
            issueB(t + 1, buf ^ 1); SB();
        }
        dsrB(buf);
        dsrA(buf, 0); SB();
        BAR(); LGKM0(); SB();
        mfmaQ(0);
        BAR();
        // phase 1: launch A(t+2) global loads; read A-quad1
        if (t + 2 < NKT) { issueAglb(t + 2); SB(); }
        dsrA(buf, 1); SB();
        BAR(); LGKM0(); SB();
        mfmaQ(1);
        BAR();
        // phase 2: read A-quad2
        dsrA(buf, 2); SB();
        BAR(); LGKM0(); SB();
        mfmaQ(2);
        BAR();
        // phase 3: certify B(t+1) (counted); read A-quad3
        dsrA(buf, 3);
        if (t + 1 < NKT) {
            if (t + 2 < NKT) { WAITV(8); } else { WAITV(0); }
        }
        SB();
        BAR(); LGKM0(); SB();
        mfmaQ(3);
        BAR();
    }

    // ---- epilogue: C/D layout col = lane&15, row = (lane>>4)*4 + j [m89] ----
    const int crow = kg * 4;
    const int ccol = frow;
    float bv[4];
#pragma unroll
    for (int n = 0; n < 4; ++n)
        bv[n] = bias[e * DOUT + n0 + wc + n * 16 + ccol];
#pragma unroll
    for (int m = 0; m < 8; ++m) {
#pragma unroll
        for (int j = 0; j < 4; ++j) {
            const int grow = row0 + wr + m * 16 + crow + j;
            if (grow < row_end) {
                float* orow = out + (size_t)grow * DOUT + n0 + wc + ccol;
#pragma unroll
                for (int n = 0; n < 4; ++n)
                    orow[n * 16] = acc[m][n][j] + bv[n];
            }
        }
    }
}

extern "C" void kernel_launch(void* const* d_in, const int* in_sizes, int n_in,
                              void* d_out, int out_size, void* d_ws, size_t ws_size,
                              hipStream_t stream) {
    const float* inp    = (const float*)d_in[0];
    const float* weight = (const float*)d_in[1];
    const float* bias   = (const float*)d_in[2];
    const int* cnt      = (const int*)d_in[3];   // int64 in reference, delivered as int32
    float* out = (float*)d_out;
    int* ws = (int*)d_ws;
    __bf16* wbf = (__bf16*)((char*)d_ws + WBF_OFF);

    hipLaunchKernelGGL(setup_tiles, dim3(1), dim3(64), 0, stream, cnt, ws);
    hipLaunchKernelGGL(wcvt, dim3(2048), dim3(256), 0, stream, weight, wbf);
    hipLaunchKernelGGL(moe_gemm, dim3(TILES_TOTAL * 2), dim3(512), 0, stream,
                       inp, wbf, bias, ws, out);
}